// Round 8
// baseline (257.812 us; speedup 1.0000x reference)
//
#include <hip/hip_runtime.h>

typedef __attribute__((ext_vector_type(8))) _Float16 f16x8;
typedef __attribute__((ext_vector_type(2))) __fp16 h16x2;
typedef __attribute__((ext_vector_type(4))) float f32x4;

#define S_LEN 2048
#define DMODEL 1024
#define NHEAD 16
#define HD 64
#define QKV_LD 3072
#define BTOT 4
#define LOG2E 1.4426950408889634f

#define GLL16(g, l)                                              \
  __builtin_amdgcn_global_load_lds(                              \
      (const __attribute__((address_space(1))) void*)(g),        \
      (__attribute__((address_space(3))) void*)(l), 16, 0, 0)

#define MFMA16(a, b, c) __builtin_amdgcn_mfma_f32_16x16x32_f16(a, b, c, 0, 0, 0)

// ---------------- fp32 -> fp16 elementwise convert ----------------
__global__ __launch_bounds__(256) void cvt_f32_f16_k(const float* __restrict__ in,
                                                     _Float16* __restrict__ out, int n) {
  int i = (blockIdx.x * 256 + threadIdx.x) * 4;
  int stride = gridDim.x * 256 * 4;
  for (; i < n; i += stride) {
    float4 v = *(const float4*)(in + i);
    _Float16 h[4];
    h[0] = (_Float16)v.x; h[1] = (_Float16)v.y; h[2] = (_Float16)v.z; h[3] = (_Float16)v.w;
    *(uint2*)(out + i) = *(const uint2*)h;
  }
}

// ---------------- fp32 [K][N] -> fp16 [N][K] transpose-convert ----------------
__global__ __launch_bounds__(256) void transpose_cvt_k(const float* __restrict__ W,
                                                       _Float16* __restrict__ Wt,
                                                       int K, int N) {
  __shared__ float t[32][33];
  int n0 = blockIdx.x * 32, k0 = blockIdx.y * 32;
  int tx = threadIdx.x, ty = threadIdx.y;  // (32,8)
#pragma unroll
  for (int i = 0; i < 32; i += 8)
    t[ty + i][tx] = W[(size_t)(k0 + ty + i) * N + n0 + tx];
  __syncthreads();
#pragma unroll
  for (int i = 0; i < 32; i += 8)
    Wt[(size_t)(n0 + ty + i) * K + k0 + tx] = (_Float16)t[tx][ty + i];
}

// ---------------- fp16 GEMM (128x128, 2-barrier): used for the proj GEMM ----
template <int OUT_F32>
__global__ __launch_bounds__(256) void gemm_bt_k(const _Float16* __restrict__ A,
                                                 const _Float16* __restrict__ Bt,
                                                 const float* __restrict__ bias,
                                                 void* __restrict__ C,
                                                 int M, int N, int K) {
  __shared__ _Float16 As[128 * 64];  // 16 KB, chunk-swizzled
  __shared__ _Float16 Bs[128 * 64];  // 16 KB, chunk-swizzled
  const int tid = threadIdx.x;
  const int wid = tid >> 6, lane = tid & 63;
  const int quad = lane >> 4, l16 = lane & 15;
  const int wr = wid >> 1, wc = wid & 1;

  const int lin = blockIdx.y * gridDim.x + blockIdx.x;
  const int width = 8 * gridDim.x;
  const int group = lin / width;
  const int pm = group * 8 + (lin % width) % 8;
  const int pn = (lin % width) / 8;
  const int tm = pm * 128, tn = pn * 128;

  const int row0 = tid >> 3;
  const int xc = 8 * ((tid & 7) ^ (row0 & 7));
  const _Float16* Ag = A + (size_t)(tm + row0) * K + xc;
  const _Float16* Bg = Bt + (size_t)(tn + row0) * K + xc;
  _Float16* AsW = &As[wid * 512];
  _Float16* BsW = &Bs[wid * 512];

  f32x4 acc[4][4] = {};

  for (int k0 = 0; k0 < K; k0 += 64) {
    __syncthreads();
#pragma unroll
    for (int p = 0; p < 4; p++) {
      GLL16(Ag + k0 + (size_t)(32 * p) * K, AsW + 2048 * p);
      GLL16(Bg + k0 + (size_t)(32 * p) * K, BsW + 2048 * p);
    }
    __syncthreads();

#pragma unroll
    for (int ks = 0; ks < 2; ks++) {
      f16x8 af[4], bf[4];
#pragma unroll
      for (int mt = 0; mt < 4; mt++)
        af[mt] = *(const f16x8*)&As[(wr * 64 + mt * 16 + l16) * 64 +
                                    (((ks * 4 + quad) ^ (l16 & 7)) << 3)];
#pragma unroll
      for (int nt = 0; nt < 4; nt++)
        bf[nt] = *(const f16x8*)&Bs[(wc * 64 + nt * 16 + l16) * 64 +
                                    (((ks * 4 + quad) ^ (l16 & 7)) << 3)];
#pragma unroll
      for (int mt = 0; mt < 4; mt++)
#pragma unroll
        for (int nt = 0; nt < 4; nt++)
          acc[mt][nt] = MFMA16(af[mt], bf[nt], acc[mt][nt]);
    }
  }

#pragma unroll
  for (int nt = 0; nt < 4; nt++) {
    int col = tn + wc * 64 + nt * 16 + l16;
    float bv = bias[col];
#pragma unroll
    for (int mt = 0; mt < 4; mt++) {
      int row = tm + wr * 64 + mt * 16 + quad * 4;
#pragma unroll
      for (int r = 0; r < 4; r++) {
        float v = acc[mt][nt][r] + bv;
        if (OUT_F32)
          ((float*)C)[(size_t)(row + r) * N + col] = v;
        else
          ((_Float16*)C)[(size_t)(row + r) * N + col] = (_Float16)v;
      }
    }
  }
}

// ---------------- fp16 GEMM 256x256, 4-phase counted-vmcnt pipeline ---------
// R14: 8-phase-style interleave (T3+T4) on the R13 geometry. Each K-tile is
// 4 phases, one C-quadrant (mh,ks) each:
//   {2 GLL(t+1) -> [vmcnt gate PH0 only] -> barrier -> ds_read quadrant frags
//    -> lgkmcnt(0) -> setprio(1) 16 MFMA setprio(0) -> barrier}
// Staging of tile t+1 is spread 2 GLL/phase DURING tile t into dbuf[(t+1)&1]
// (never read by tile t; tile t-1's readers lgkm'd before its last barrier ->
// race-free). vmcnt gate once per tile at PH0: after issuing t+1's first A
// pair, wait vmcnt(2) (= all of tile t's 8 landed; 2 newer in flight). Net
// in-flight 2..10, never drained mid-loop. Barriers uniform 8/tile.
__global__ __launch_bounds__(512, 2) void gemm256_k(const _Float16* __restrict__ A,
                                                    const _Float16* __restrict__ Bt,
                                                    const float* __restrict__ bias,
                                                    _Float16* __restrict__ C,
                                                    int M, int N, int K) {
  __shared__ __align__(16) _Float16 sb[2][2][16384];  // [dbuf][A/B][256x64] 128 KB
  const int tid = threadIdx.x;
  const int wid = tid >> 6, lane = tid & 63;
  const int quad = lane >> 4, l16 = lane & 15;
  const int wm = wid >> 2, wn = wid & 3;

  const int lin = blockIdx.y * gridDim.x + blockIdx.x;
  const int width = 8 * gridDim.x;
  const int group = lin / width;
  const int pm = group * 8 + (lin % width) % 8;
  const int pn = (lin % width) / 8;
  const int tm = pm * 256, tn = pn * 256;

  const int row0 = tid >> 3;  // 0..63
  const int xc = 8 * ((tid & 7) ^ (row0 & 7));
  const _Float16* Ag = A + (size_t)(tm + row0) * K + xc;
  const _Float16* Bg = Bt + (size_t)(tn + row0) * K + xc;

  f32x4 acc[8][4] = {};
  const int ntk = K >> 6;

  auto sA = [&](int t, int r) {
    GLL16(Ag + (t << 6) + (size_t)(64 * r) * K, &sb[t & 1][0][r * 4096 + wid * 512]);
  };
  auto sB = [&](int t, int r) {
    GLL16(Bg + (t << 6) + (size_t)(64 * r) * K, &sb[t & 1][1][r * 4096 + wid * 512]);
  };

  // prologue: stage tile 0 fully
#pragma unroll
  for (int r = 0; r < 4; r++) { sA(0, r); sB(0, r); }

  for (int t = 0; t < ntk; t++) {
    const _Float16* As_ = sb[t & 1][0];
    const _Float16* Bs_ = sb[t & 1][1];
    const bool pf = (t + 1 < ntk);
    f16x8 bf[2][4];  // [ks][n] — bf lives across mh phases
    f16x8 af[4];

    // ---------------- PH0: (mh0, ks0) ----------------
    if (pf) {
      sA(t + 1, 0); sA(t + 1, 1);
      asm volatile("s_waitcnt vmcnt(2)" ::: "memory");
    } else {
      asm volatile("s_waitcnt vmcnt(0)" ::: "memory");
    }
    __builtin_amdgcn_s_barrier();
    __builtin_amdgcn_sched_barrier(0);
#pragma unroll
    for (int n = 0; n < 4; n++)
      bf[0][n] = *(const f16x8*)&Bs_[(wn * 64 + n * 16 + l16) * 64 +
                                     ((quad ^ (l16 & 7)) << 3)];
#pragma unroll
    for (int m = 0; m < 4; m++)
      af[m] = *(const f16x8*)&As_[(wm * 128 + m * 16 + l16) * 64 +
                                  ((quad ^ (l16 & 7)) << 3)];
    asm volatile("s_waitcnt lgkmcnt(0)" ::: "memory");
    __builtin_amdgcn_sched_barrier(0);
    __builtin_amdgcn_s_setprio(1);
#pragma unroll
    for (int m = 0; m < 4; m++)
#pragma unroll
      for (int n = 0; n < 4; n++)
        acc[m][n] = MFMA16(af[m], bf[0][n], acc[m][n]);
    __builtin_amdgcn_s_setprio(0);
    __builtin_amdgcn_s_barrier();
    __builtin_amdgcn_sched_barrier(0);

    // ---------------- PH1: (mh0, ks1) ----------------
    if (pf) { sA(t + 1, 2); sA(t + 1, 3); }
#pragma unroll
    for (int n = 0; n < 4; n++)
      bf[1][n] = *(const f16x8*)&Bs_[(wn * 64 + n * 16 + l16) * 64 +
                                     (((4 + quad) ^ (l16 & 7)) << 3)];
#pragma unroll
    for (int m = 0; m < 4; m++)
      af[m] = *(const f16x8*)&As_[(wm * 128 + m * 16 + l16) * 64 +
                                  (((4 + quad) ^ (l16 & 7)) << 3)];
    asm volatile("s_waitcnt lgkmcnt(0)" ::: "memory");
    __builtin_amdgcn_sched_barrier(0);
    __builtin_amdgcn_s_setprio(1);
#pragma unroll
    for (int m = 0; m < 4; m++)
#pragma unroll
      for (int n = 0; n < 4; n++)
        acc[m][n] = MFMA16(af[m], bf[1][n], acc[m][n]);
    __builtin_amdgcn_s_setprio(0);
    __builtin_amdgcn_s_barrier();
    __builtin_amdgcn_sched_barrier(0);

    // ---------------- PH2: (mh1, ks0) ----------------
    if (pf) { sB(t + 1, 0); sB(t + 1, 1); }
#pragma unroll
    for (int m = 0; m < 4; m++)
      af[m] = *(const f16x8*)&As_[(wm * 128 + 64 + m * 16 + l16) * 64 +
                                  ((quad ^ (l16 & 7)) << 3)];
    asm volatile("s_waitcnt lgkmcnt(0)" ::: "memory");
    __builtin_amdgcn_sched_barrier(0);
    __builtin_amdgcn_s_setprio(1);
#pragma unroll
    for (int m = 0; m < 4; m++)
#pragma unroll
      for (int n = 0; n < 4; n++)
        acc[4 + m][n] = MFMA16(af[m], bf[0][n], acc[4 + m][n]);
    __builtin_amdgcn_s_setprio(0);
    __builtin_amdgcn_s_barrier();
    __builtin_amdgcn_sched_barrier(0);

    // ---------------- PH3: (mh1, ks1) ----------------
    if (pf) { sB(t + 1, 2); sB(t + 1, 3); }
#pragma unroll
    for (int m = 0; m < 4; m++)
      af[m] = *(const f16x8*)&As_[(wm * 128 + 64 + m * 16 + l16) * 64 +
                                  (((4 + quad) ^ (l16 & 7)) << 3)];
    asm volatile("s_waitcnt lgkmcnt(0)" ::: "memory");
    __builtin_amdgcn_sched_barrier(0);
    __builtin_amdgcn_s_setprio(1);
#pragma unroll
    for (int m = 0; m < 4; m++)
#pragma unroll
      for (int n = 0; n < 4; n++)
        acc[4 + m][n] = MFMA16(af[m], bf[1][n], acc[4 + m][n]);
    __builtin_amdgcn_s_setprio(0);
    __builtin_amdgcn_s_barrier();
    __builtin_amdgcn_sched_barrier(0);
  }

  // epilogue: bias + f16 store
#pragma unroll
  for (int n = 0; n < 4; n++) {
    int col = tn + wn * 64 + n * 16 + l16;
    float bv = bias[col];
#pragma unroll
    for (int m8 = 0; m8 < 8; m8++) {
      int row = tm + wm * 128 + m8 * 16 + quad * 4;
#pragma unroll
      for (int r = 0; r < 4; r++)
        C[(size_t)(row + r) * N + col] = (_Float16)(acc[m8][n][r] + bv);
    }
  }
}

// ---------------- fused causal flash attention ----------------
// R12 structure (unchanged): static-max softmax (constant shift m=4 folded
// into MFMA C-init; exact math, shift cancels in the division), q x k wave
// split (8 waves = 4 qg x 2 kg), paired blocks (bh,p) run q-tiles p then
// 15-p (uniform 34 iters), double-buffered GLL K + pair-pack V^T,
// 1 barrier/iter, kg-halves merge o=o0+o1, l=l0+l1 in the epilogue.
__global__ __launch_bounds__(512, 4) void attn_k(const _Float16* __restrict__ qkv,
                                                 _Float16* __restrict__ out) {
  __shared__ __align__(16) char pool[53760];
  _Float16* KsB = (_Float16*)pool;
  _Float16* VTsB = (_Float16*)(pool + 16384);

  const int tid = threadIdx.x, wid = tid >> 6, lane = tid & 63;
  const int quad = lane >> 4, l16 = lane & 15;
  const int qg = wid & 3, kg = wid >> 2;
  _Float16* PsW = (_Float16*)(pool + 32768) + wid * 1280;
  const int bh = blockIdx.x, b = bh >> 4, h = bh & 15;
  const int p = blockIdx.y;  // 0..7
  const _Float16* base = qkv + (size_t)b * S_LEN * QKV_LD + h * HD;

  const int krow = tid >> 3;
  const _Float16* Kg = base + DMODEL + (size_t)krow * QKV_LD +
                       8 * ((tid & 7) ^ (krow & 7));
  const bool vstager = (tid < 256);
  const int kp = tid & 31, dbase = ((tid >> 5) & 7) * 8;
  const _Float16* Vg = base + 2 * DMODEL + (size_t)(2 * kp) * QKV_LD + dbase;

  int voff[8];
#pragma unroll
  for (int i = 0; i < 8; i++) {
    int d = dbase + i;
    voff[i] = d * 32 + (((kp >> 2) ^ (d & 7)) << 2) + (kp & 3);
  }

  auto stage_V = [&](int bufi, uint4 v0, uint4 v1) {
    union { uint4 u; _Float16 h[8]; } a, c;
    a.u = v0; c.u = v1;
    uint* VT32 = (uint*)(VTsB + bufi * 4096);
#pragma unroll
    for (int i = 0; i < 8; i++) {
      union { _Float16 h[2]; uint u; } w;
      w.h[0] = a.h[i]; w.h[1] = c.h[i];
      VT32[voff[i]] = w.u;
    }
  };

  auto run_pass = [&](int qt) {
    f16x8 bq[2][2];  // [nt][ks]
    {
      const _Float16 qs = (_Float16)(0.125f * LOG2E);
#pragma unroll
      for (int nt = 0; nt < 2; nt++)
#pragma unroll
        for (int ks = 0; ks < 2; ks++) {
          union { uint4 u; f16x8 h; } v;
          v.u = *(const uint4*)(base +
                                (size_t)(qt + qg * 32 + nt * 16 + l16) * QKV_LD +
                                ks * 32 + quad * 8);
          bq[nt][ks] = v.h * qs;
        }
    }

    float l_i[2] = {0.f, 0.f};
    f32x4 o[4][2] = {};

    const int qmin_w = qt + qg * 32;
    const int qmax_w = qmin_w + 31;
    const int nj = qt / 64 + 2;

    __syncthreads();
    GLL16(Kg, KsB + wid * 512);
    if (vstager) stage_V(0, *(const uint4*)(Vg), *(const uint4*)(Vg + QKV_LD));
    __syncthreads();

    for (int j = 0; j < nj; j++) {
      const int cur = j & 1, nxt = cur ^ 1;
      const int k0g = j * 64;
      const bool pf = (j + 1 < nj);
      uint4 pv0, pv1;
      if (pf) {
        const int kn = k0g + 64;
        GLL16(Kg + (size_t)kn * QKV_LD, KsB + nxt * 4096 + wid * 512);
        if (vstager) {
          pv0 = *(const uint4*)(Vg + (size_t)kn * QKV_LD);
          pv1 = *(const uint4*)(Vg + (size_t)(kn + 1) * QKV_LD);
        }
      }

      const int kgbase = k0g + kg * 32;
      if (kgbase <= qmax_w) {
        const _Float16* Kc = KsB + cur * 4096;
        f32x4 sc[2][2];
#pragma unroll
        for (int mt = 0; mt < 2; mt++)
#pragma unroll
          for (int nt = 0; nt < 2; nt++)
            sc[mt][nt] = f32x4{-4.f, -4.f, -4.f, -4.f};
#pragma unroll
        for (int ks = 0; ks < 2; ks++)
#pragma unroll
          for (int mt = 0; mt < 2; mt++) {
            f16x8 ak = *(const f16x8*)&Kc[(kg * 32 + mt * 16 + l16) * 64 +
                                          (((ks * 4 + quad) ^ (l16 & 7)) << 3)];
            sc[mt][0] = MFMA16(ak, bq[0][ks], sc[mt][0]);
            sc[mt][1] = MFMA16(ak, bq[1][ks], sc[mt][1]);
          }

        const bool need_mask = (kgbase + 31 > qmin_w);
#pragma unroll
        for (int nt = 0; nt < 2; nt++) {
          const int qgl = qmin_w + nt * 16 + l16;
          float pe[8];
#pragma unroll
          for (int mt = 0; mt < 2; mt++)
#pragma unroll
            for (int r = 0; r < 4; r++) {
              float v = sc[mt][nt][r];
              if (need_mask) {
                int kgi = kgbase + mt * 16 + quad * 4 + r;
                v = (kgi <= qgl) ? v : -3.0e38f;
              }
              pe[mt * 4 + r] = __builtin_amdgcn_exp2f(v);
            }
          l_i[nt] += ((pe[0] + pe[1]) + (pe[2] + pe[3])) +
                     ((pe[4] + pe[5]) + (pe[6] + pe[7]));
#pragma unroll
          for (int mt = 0; mt < 2; mt++) {
            union { h16x2 h[2]; uint2 u; } w;
            w.h[0] = __builtin_amdgcn_cvt_pkrtz(pe[mt * 4 + 0], pe[mt * 4 + 1]);
            w.h[1] = __builtin_amdgcn_cvt_pkrtz(pe[mt * 4 + 2], pe[mt * 4 + 3]);
            *(uint2*)&PsW[(nt * 16 + l16) * 40 + mt * 16 + quad * 4] = w.u;
          }
        }

        const _Float16* Vc = VTsB + cur * 4096;
        f16x8 bp0 = *(const f16x8*)&PsW[l16 * 40 + quad * 8];
        f16x8 bp1 = *(const f16x8*)&PsW[(16 + l16) * 40 + quad * 8];
#pragma unroll
        for (int md = 0; md < 4; md++) {
          f16x8 av = *(const f16x8*)&Vc[(md * 16 + l16) * 64 +
                                        (((kg * 4 + quad) ^ (l16 & 7)) << 3)];
          o[md][0] = MFMA16(av, bp0, o[md][0]);
          o[md][1] = MFMA16(av, bp1, o[md][1]);
        }
      }

      if (pf && vstager) stage_V(nxt, pv0, pv1);
      __syncthreads();
    }

#pragma unroll
    for (int nt = 0; nt < 2; nt++) {
      float r = l_i[nt];
      r += __shfl_xor(r, 16, 64);
      r += __shfl_xor(r, 32, 64);
      l_i[nt] = r;
    }
    float* X = (float*)pool;
    float* ML = (float*)(pool + 53248);
    if (kg == 1) {
#pragma unroll
      for (int md = 0; md < 4; md++)
#pragma unroll
        for (int nt = 0; nt < 2; nt++)
          *(f32x4*)&X[qg * 2048 + (md * 2 + nt) * 256 + lane * 4] = o[md][nt];
      if (quad == 0) {
#pragma unroll
        for (int nt = 0; nt < 2; nt++)
          ML[(qg * 2 + nt) * 16 + l16] = l_i[nt];
      }
    }
    __syncthreads();
    if (kg == 0) {
      _Float16* PsE = (_Float16*)(pool + 32768) + qg * 2304;
      float inv[2];
#pragma unroll
      for (int nt = 0; nt < 2; nt++)
        inv[nt] = 1.0f / (l_i[nt] + ML[(qg * 2 + nt) * 16 + l16]);
#pragma unroll
      for (int md = 0; md < 4; md++)
#pragma unroll
        for (int nt = 0; nt < 2; nt++) {
          f32x4 o1 = *(const f32x4*)&X[qg * 2048 + (md * 2 + nt) * 256 + lane * 4];
          f32x4 ot = o[md][nt] + o1;
          union { h16x2 h[2]; uint2 u; } w;
          w.h[0] = __builtin_amdgcn_cvt_pkrtz(ot[0] * inv[nt], ot[1] * inv[nt]);
          w.h[1] = __builtin_amdgcn_cvt_pkrtz(ot[2] * inv[nt], ot[3] * inv[nt]);
          *(uint2*)&PsE[(nt * 16 + l16) * 72 + md * 16 + quad * 4] = w.u;
        }
      {
        int r = lane >> 1, ch = (lane & 1) * 32;
        const int qgl = qt + qg * 32 + r;
        _Float16* orow = out + (size_t)(b * S_LEN + qgl) * DMODEL + h * HD + ch;
#pragma unroll
        for (int i = 0; i < 4; i++)
          *(uint4*)(orow + i * 8) = *(const uint4*)&PsE[r * 72 + ch + i * 8];
      }
    }
  };

  run_pass(p * 128);
  run_pass((15 - p) * 128);
}

// ---------------- launcher ----------------
extern "C" void kernel_launch(void* const* d_in, const int* in_sizes, int n_in,
                              void* d_out, int out_size, void* d_ws, size_t ws_size,
                              hipStream_t stream) {
  const float* x = (const float*)d_in[0];
  const float* w_attn = (const float*)d_in[1];
  const float* b_attn = (const float*)d_in[2];
  const float* w_proj = (const float*)d_in[3];
  const float* b_proj = (const float*)d_in[4];
  float* outp = (float*)d_out;

  char* ws = (char*)d_ws;
  _Float16* x16 = (_Float16*)ws;                         // 16,777,216 B
  _Float16* wTa = (_Float16*)(ws + 16777216);            //  6,291,456 B
  _Float16* wTp = (_Float16*)(ws + 16777216 + 6291456);  //  2,097,152 B
  _Float16* qkv = (_Float16*)(ws + 25165824);            // 50,331,648 B
  _Float16* abuf = (_Float16*)(ws + 75497472);           // 16,777,216 B

  const int nx = BTOT * S_LEN * DMODEL;

  cvt_f32_f16_k<<<8192, 256, 0, stream>>>(x, x16, nx);
  transpose_cvt_k<<<dim3(QKV_LD / 32, DMODEL / 32), dim3(32, 8), 0, stream>>>(
      w_attn, wTa, DMODEL, QKV_LD);
  transpose_cvt_k<<<dim3(DMODEL / 32, DMODEL / 32), dim3(32, 8), 0, stream>>>(
      w_proj, wTp, DMODEL, DMODEL);

  gemm256_k<<<dim3(QKV_LD / 256, BTOT * S_LEN / 256), 512, 0, stream>>>(
      x16, wTa, b_attn, qkv, BTOT * S_LEN, QKV_LD, DMODEL);

  attn_k<<<dim3(BTOT * NHEAD, 8), 512, 0, stream>>>(qkv, abuf);

  gemm_bt_k<1><<<dim3(DMODEL / 128, BTOT * S_LEN / 128), 256, 0, stream>>>(
      abuf, wTp, b_proj, outp, BTOT * S_LEN, DMODEL, DMODEL);
}

// Round 9
// 253.316 us; speedup vs baseline: 1.0177x; 1.0177x over previous
//
#include <hip/hip_runtime.h>

typedef __attribute__((ext_vector_type(8))) _Float16 f16x8;
typedef __attribute__((ext_vector_type(2))) __fp16 h16x2;
typedef __attribute__((ext_vector_type(4))) float f32x4;

#define S_LEN 2048
#define DMODEL 1024
#define NHEAD 16
#define HD 64
#define QKV_LD 3072
#define BTOT 4
#define LOG2E 1.4426950408889634f

#define GLL16(g, l)                                              \
  __builtin_amdgcn_global_load_lds(                              \
      (const __attribute__((address_space(1))) void*)(g),        \
      (__attribute__((address_space(3))) void*)(l), 16, 0, 0)

#define MFMA16(a, b, c) __builtin_amdgcn_mfma_f32_16x16x32_f16(a, b, c, 0, 0, 0)

// ---------------- fp32 -> fp16 elementwise convert ----------------
__global__ __launch_bounds__(256) void cvt_f32_f16_k(const float* __restrict__ in,
                                                     _Float16* __restrict__ out, int n) {
  int i = (blockIdx.x * 256 + threadIdx.x) * 4;
  int stride = gridDim.x * 256 * 4;
  for (; i < n; i += stride) {
    float4 v = *(const float4*)(in + i);
    _Float16 h[4];
    h[0] = (_Float16)v.x; h[1] = (_Float16)v.y; h[2] = (_Float16)v.z; h[3] = (_Float16)v.w;
    *(uint2*)(out + i) = *(const uint2*)h;
  }
}

// ---------------- fp32 [K][N] -> fp16 [N][K] transpose-convert ----------------
__global__ __launch_bounds__(256) void transpose_cvt_k(const float* __restrict__ W,
                                                       _Float16* __restrict__ Wt,
                                                       int K, int N) {
  __shared__ float t[32][33];
  int n0 = blockIdx.x * 32, k0 = blockIdx.y * 32;
  int tx = threadIdx.x, ty = threadIdx.y;  // (32,8)
#pragma unroll
  for (int i = 0; i < 32; i += 8)
    t[ty + i][tx] = W[(size_t)(k0 + ty + i) * N + n0 + tx];
  __syncthreads();
#pragma unroll
  for (int i = 0; i < 32; i += 8)
    Wt[(size_t)(n0 + ty + i) * K + k0 + tx] = (_Float16)t[tx][ty + i];
}

// ---------------- fp16 GEMM (128x128, 2-barrier): used for the proj GEMM ----
template <int OUT_F32>
__global__ __launch_bounds__(256) void gemm_bt_k(const _Float16* __restrict__ A,
                                                 const _Float16* __restrict__ Bt,
                                                 const float* __restrict__ bias,
                                                 void* __restrict__ C,
                                                 int M, int N, int K) {
  __shared__ _Float16 As[128 * 64];  // 16 KB, chunk-swizzled
  __shared__ _Float16 Bs[128 * 64];  // 16 KB, chunk-swizzled
  const int tid = threadIdx.x;
  const int wid = tid >> 6, lane = tid & 63;
  const int quad = lane >> 4, l16 = lane & 15;
  const int wr = wid >> 1, wc = wid & 1;

  const int lin = blockIdx.y * gridDim.x + blockIdx.x;
  const int width = 8 * gridDim.x;
  const int group = lin / width;
  const int pm = group * 8 + (lin % width) % 8;
  const int pn = (lin % width) / 8;
  const int tm = pm * 128, tn = pn * 128;

  const int row0 = tid >> 3;
  const int xc = 8 * ((tid & 7) ^ (row0 & 7));
  const _Float16* Ag = A + (size_t)(tm + row0) * K + xc;
  const _Float16* Bg = Bt + (size_t)(tn + row0) * K + xc;
  _Float16* AsW = &As[wid * 512];
  _Float16* BsW = &Bs[wid * 512];

  f32x4 acc[4][4] = {};

  for (int k0 = 0; k0 < K; k0 += 64) {
    __syncthreads();
#pragma unroll
    for (int p = 0; p < 4; p++) {
      GLL16(Ag + k0 + (size_t)(32 * p) * K, AsW + 2048 * p);
      GLL16(Bg + k0 + (size_t)(32 * p) * K, BsW + 2048 * p);
    }
    __syncthreads();

#pragma unroll
    for (int ks = 0; ks < 2; ks++) {
      f16x8 af[4], bf[4];
#pragma unroll
      for (int mt = 0; mt < 4; mt++)
        af[mt] = *(const f16x8*)&As[(wr * 64 + mt * 16 + l16) * 64 +
                                    (((ks * 4 + quad) ^ (l16 & 7)) << 3)];
#pragma unroll
      for (int nt = 0; nt < 4; nt++)
        bf[nt] = *(const f16x8*)&Bs[(wc * 64 + nt * 16 + l16) * 64 +
                                    (((ks * 4 + quad) ^ (l16 & 7)) << 3)];
#pragma unroll
      for (int mt = 0; mt < 4; mt++)
#pragma unroll
        for (int nt = 0; nt < 4; nt++)
          acc[mt][nt] = MFMA16(af[mt], bf[nt], acc[mt][nt]);
    }
  }

#pragma unroll
  for (int nt = 0; nt < 4; nt++) {
    int col = tn + wc * 64 + nt * 16 + l16;
    float bv = bias[col];
#pragma unroll
    for (int mt = 0; mt < 4; mt++) {
      int row = tm + wr * 64 + mt * 16 + quad * 4;
#pragma unroll
      for (int r = 0; r < 4; r++) {
        float v = acc[mt][nt][r] + bv;
        if (OUT_F32)
          ((float*)C)[(size_t)(row + r) * N + col] = v;
        else
          ((_Float16*)C)[(size_t)(row + r) * N + col] = (_Float16)v;
      }
    }
  }
}

// ---------------- fp16 GEMM 256x256, 4-phase pipelined ds_reads -------------
// R15: m201-faithful phase ordering on the R14 geometry. Defect fixed vs R14:
// ds_reads for phase p are now issued in phase p-1 BEFORE its closing barrier,
// so their latency hides under the barrier-wait + other waves' MFMA; only
// PH0's reads (new K-tile buffer, gated by vmcnt+barrier) remain exposed.
// Staging of tile t+1: 4 A-GLLs at PH0, 4 B-GLLs at PH1 (last GLL has ~3
// phases to land before its gate at t+1 PH0). vmcnt(4) gate once per tile
// (t's 8 landed, t+1's 4 A in flight; never drained mid-loop). Race audit:
// reads of buffer t all lgkm-complete before PH3's closing barrier; writes to
// that buffer (tile t+2) issue only after it. Barriers uniform 5/tile.
__global__ __launch_bounds__(512, 2) void gemm256_k(const _Float16* __restrict__ A,
                                                    const _Float16* __restrict__ Bt,
                                                    const float* __restrict__ bias,
                                                    _Float16* __restrict__ C,
                                                    int M, int N, int K) {
  __shared__ __align__(16) _Float16 sb[2][2][16384];  // [dbuf][A/B][256x64] 128 KB
  const int tid = threadIdx.x;
  const int wid = tid >> 6, lane = tid & 63;
  const int quad = lane >> 4, l16 = lane & 15;
  const int wm = wid >> 2, wn = wid & 3;

  const int lin = blockIdx.y * gridDim.x + blockIdx.x;
  const int width = 8 * gridDim.x;
  const int group = lin / width;
  const int pm = group * 8 + (lin % width) % 8;
  const int pn = (lin % width) / 8;
  const int tm = pm * 256, tn = pn * 256;

  const int row0 = tid >> 3;  // 0..63
  const int xc = 8 * ((tid & 7) ^ (row0 & 7));
  const _Float16* Ag = A + (size_t)(tm + row0) * K + xc;
  const _Float16* Bg = Bt + (size_t)(tn + row0) * K + xc;

  f32x4 acc[8][4] = {};
  const int ntk = K >> 6;

  auto sA = [&](int t, int r) {
    GLL16(Ag + (t << 6) + (size_t)(64 * r) * K, &sb[t & 1][0][r * 4096 + wid * 512]);
  };
  auto sB = [&](int t, int r) {
    GLL16(Bg + (t << 6) + (size_t)(64 * r) * K, &sb[t & 1][1][r * 4096 + wid * 512]);
  };

  // prologue: stage tile 0 fully
#pragma unroll
  for (int r = 0; r < 4; r++) { sA(0, r); sB(0, r); }

  for (int t = 0; t < ntk; t++) {
    const _Float16* As_ = sb[t & 1][0];
    const _Float16* Bs_ = sb[t & 1][1];
    const bool pf = (t + 1 < ntk);
    f16x8 bf[2][4];  // [ks][n]
    f16x8 af[2][4];  // two live sets, statically indexed

    // ---------------- PH0: (mh0, ks0) ----------------
    if (pf) {
      sA(t + 1, 0); sA(t + 1, 1); sA(t + 1, 2); sA(t + 1, 3);
      asm volatile("s_waitcnt vmcnt(4)" ::: "memory");
    } else {
      asm volatile("s_waitcnt vmcnt(0)" ::: "memory");
    }
    __builtin_amdgcn_s_barrier();
    __builtin_amdgcn_sched_barrier(0);
    // only exposed reads of the tile: (mh0,ks0) frags + all ks0 B frags
#pragma unroll
    for (int n = 0; n < 4; n++)
      bf[0][n] = *(const f16x8*)&Bs_[(wn * 64 + n * 16 + l16) * 64 +
                                     ((quad ^ (l16 & 7)) << 3)];
#pragma unroll
    for (int m = 0; m < 4; m++)
      af[0][m] = *(const f16x8*)&As_[(wm * 128 + m * 16 + l16) * 64 +
                                     ((quad ^ (l16 & 7)) << 3)];
    asm volatile("s_waitcnt lgkmcnt(0)" ::: "memory");
    __builtin_amdgcn_sched_barrier(0);
    __builtin_amdgcn_s_setprio(1);
#pragma unroll
    for (int m = 0; m < 4; m++)
#pragma unroll
      for (int n = 0; n < 4; n++)
        acc[m][n] = MFMA16(af[0][m], bf[0][n], acc[m][n]);
    __builtin_amdgcn_s_setprio(0);
    // pre-issue PH1's reads (mh0, ks1); latency hides under the barrier
#pragma unroll
    for (int n = 0; n < 4; n++)
      bf[1][n] = *(const f16x8*)&Bs_[(wn * 64 + n * 16 + l16) * 64 +
                                     (((4 + quad) ^ (l16 & 7)) << 3)];
#pragma unroll
    for (int m = 0; m < 4; m++)
      af[1][m] = *(const f16x8*)&As_[(wm * 128 + m * 16 + l16) * 64 +
                                     (((4 + quad) ^ (l16 & 7)) << 3)];
    __builtin_amdgcn_sched_barrier(0);
    __builtin_amdgcn_s_barrier();
    __builtin_amdgcn_sched_barrier(0);

    // ---------------- PH1: (mh0, ks1) ----------------
    if (pf) { sB(t + 1, 0); sB(t + 1, 1); sB(t + 1, 2); sB(t + 1, 3); }
    asm volatile("s_waitcnt lgkmcnt(0)" ::: "memory");
    __builtin_amdgcn_sched_barrier(0);
    __builtin_amdgcn_s_setprio(1);
#pragma unroll
    for (int m = 0; m < 4; m++)
#pragma unroll
      for (int n = 0; n < 4; n++)
        acc[m][n] = MFMA16(af[1][m], bf[1][n], acc[m][n]);
    __builtin_amdgcn_s_setprio(0);
    // pre-issue PH2's reads (mh1, ks0)
#pragma unroll
    for (int m = 0; m < 4; m++)
      af[0][m] = *(const f16x8*)&As_[(wm * 128 + 64 + m * 16 + l16) * 64 +
                                     ((quad ^ (l16 & 7)) << 3)];
    __builtin_amdgcn_sched_barrier(0);
    __builtin_amdgcn_s_barrier();
    __builtin_amdgcn_sched_barrier(0);

    // ---------------- PH2: (mh1, ks0) ----------------
    asm volatile("s_waitcnt lgkmcnt(0)" ::: "memory");
    __builtin_amdgcn_sched_barrier(0);
    __builtin_amdgcn_s_setprio(1);
#pragma unroll
    for (int m = 0; m < 4; m++)
#pragma unroll
      for (int n = 0; n < 4; n++)
        acc[4 + m][n] = MFMA16(af[0][m], bf[0][n], acc[4 + m][n]);
    __builtin_amdgcn_s_setprio(0);
    // pre-issue PH3's reads (mh1, ks1)
#pragma unroll
    for (int m = 0; m < 4; m++)
      af[1][m] = *(const f16x8*)&As_[(wm * 128 + 64 + m * 16 + l16) * 64 +
                                     (((4 + quad) ^ (l16 & 7)) << 3)];
    __builtin_amdgcn_sched_barrier(0);
    __builtin_amdgcn_s_barrier();
    __builtin_amdgcn_sched_barrier(0);

    // ---------------- PH3: (mh1, ks1) ----------------
    asm volatile("s_waitcnt lgkmcnt(0)" ::: "memory");
    __builtin_amdgcn_sched_barrier(0);
    __builtin_amdgcn_s_setprio(1);
#pragma unroll
    for (int m = 0; m < 4; m++)
#pragma unroll
      for (int n = 0; n < 4; n++)
        acc[4 + m][n] = MFMA16(af[1][m], bf[1][n], acc[4 + m][n]);
    __builtin_amdgcn_s_setprio(0);
    __builtin_amdgcn_sched_barrier(0);
    __builtin_amdgcn_s_barrier();
    __builtin_amdgcn_sched_barrier(0);
  }

  // epilogue: bias + f16 store
#pragma unroll
  for (int n = 0; n < 4; n++) {
    int col = tn + wn * 64 + n * 16 + l16;
    float bv = bias[col];
#pragma unroll
    for (int m8 = 0; m8 < 8; m8++) {
      int row = tm + wm * 128 + m8 * 16 + quad * 4;
#pragma unroll
      for (int r = 0; r < 4; r++)
        C[(size_t)(row + r) * N + col] = (_Float16)(acc[m8][n][r] + bv);
    }
  }
}

// ---------------- fused causal flash attention ----------------
// R12 structure (unchanged): static-max softmax (constant shift m=4 folded
// into MFMA C-init; exact math, shift cancels in the division), q x k wave
// split (8 waves = 4 qg x 2 kg), paired blocks (bh,p) run q-tiles p then
// 15-p (uniform 34 iters), double-buffered GLL K + pair-pack V^T,
// 1 barrier/iter, kg-halves merge o=o0+o1, l=l0+l1 in the epilogue.
__global__ __launch_bounds__(512, 4) void attn_k(const _Float16* __restrict__ qkv,
                                                 _Float16* __restrict__ out) {
  __shared__ __align__(16) char pool[53760];
  _Float16* KsB = (_Float16*)pool;
  _Float16* VTsB = (_Float16*)(pool + 16384);

  const int tid = threadIdx.x, wid = tid >> 6, lane = tid & 63;
  const int quad = lane >> 4, l16 = lane & 15;
  const int qg = wid & 3, kg = wid >> 2;
  _Float16* PsW = (_Float16*)(pool + 32768) + wid * 1280;
  const int bh = blockIdx.x, b = bh >> 4, h = bh & 15;
  const int p = blockIdx.y;  // 0..7
  const _Float16* base = qkv + (size_t)b * S_LEN * QKV_LD + h * HD;

  const int krow = tid >> 3;
  const _Float16* Kg = base + DMODEL + (size_t)krow * QKV_LD +
                       8 * ((tid & 7) ^ (krow & 7));
  const bool vstager = (tid < 256);
  const int kp = tid & 31, dbase = ((tid >> 5) & 7) * 8;
  const _Float16* Vg = base + 2 * DMODEL + (size_t)(2 * kp) * QKV_LD + dbase;

  int voff[8];
#pragma unroll
  for (int i = 0; i < 8; i++) {
    int d = dbase + i;
    voff[i] = d * 32 + (((kp >> 2) ^ (d & 7)) << 2) + (kp & 3);
  }

  auto stage_V = [&](int bufi, uint4 v0, uint4 v1) {
    union { uint4 u; _Float16 h[8]; } a, c;
    a.u = v0; c.u = v1;
    uint* VT32 = (uint*)(VTsB + bufi * 4096);
#pragma unroll
    for (int i = 0; i < 8; i++) {
      union { _Float16 h[2]; uint u; } w;
      w.h[0] = a.h[i]; w.h[1] = c.h[i];
      VT32[voff[i]] = w.u;
    }
  };

  auto run_pass = [&](int qt) {
    f16x8 bq[2][2];  // [nt][ks]
    {
      const _Float16 qs = (_Float16)(0.125f * LOG2E);
#pragma unroll
      for (int nt = 0; nt < 2; nt++)
#pragma unroll
        for (int ks = 0; ks < 2; ks++) {
          union { uint4 u; f16x8 h; } v;
          v.u = *(const uint4*)(base +
                                (size_t)(qt + qg * 32 + nt * 16 + l16) * QKV_LD +
                                ks * 32 + quad * 8);
          bq[nt][ks] = v.h * qs;
        }
    }

    float l_i[2] = {0.f, 0.f};
    f32x4 o[4][2] = {};

    const int qmin_w = qt + qg * 32;
    const int qmax_w = qmin_w + 31;
    const int nj = qt / 64 + 2;

    __syncthreads();
    GLL16(Kg, KsB + wid * 512);
    if (vstager) stage_V(0, *(const uint4*)(Vg), *(const uint4*)(Vg + QKV_LD));
    __syncthreads();

    for (int j = 0; j < nj; j++) {
      const int cur = j & 1, nxt = cur ^ 1;
      const int k0g = j * 64;
      const bool pf = (j + 1 < nj);
      uint4 pv0, pv1;
      if (pf) {
        const int kn = k0g + 64;
        GLL16(Kg + (size_t)kn * QKV_LD, KsB + nxt * 4096 + wid * 512);
        if (vstager) {
          pv0 = *(const uint4*)(Vg + (size_t)kn * QKV_LD);
          pv1 = *(const uint4*)(Vg + (size_t)(kn + 1) * QKV_LD);
        }
      }

      const int kgbase = k0g + kg * 32;
      if (kgbase <= qmax_w) {
        const _Float16* Kc = KsB + cur * 4096;
        f32x4 sc[2][2];
#pragma unroll
        for (int mt = 0; mt < 2; mt++)
#pragma unroll
          for (int nt = 0; nt < 2; nt++)
            sc[mt][nt] = f32x4{-4.f, -4.f, -4.f, -4.f};
#pragma unroll
        for (int ks = 0; ks < 2; ks++)
#pragma unroll
          for (int mt = 0; mt < 2; mt++) {
            f16x8 ak = *(const f16x8*)&Kc[(kg * 32 + mt * 16 + l16) * 64 +
                                          (((ks * 4 + quad) ^ (l16 & 7)) << 3)];
            sc[mt][0] = MFMA16(ak, bq[0][ks], sc[mt][0]);
            sc[mt][1] = MFMA16(ak, bq[1][ks], sc[mt][1]);
          }

        const bool need_mask = (kgbase + 31 > qmin_w);
#pragma unroll
        for (int nt = 0; nt < 2; nt++) {
          const int qgl = qmin_w + nt * 16 + l16;
          float pe[8];
#pragma unroll
          for (int mt = 0; mt < 2; mt++)
#pragma unroll
            for (int r = 0; r < 4; r++) {
              float v = sc[mt][nt][r];
              if (need_mask) {
                int kgi = kgbase + mt * 16 + quad * 4 + r;
                v = (kgi <= qgl) ? v : -3.0e38f;
              }
              pe[mt * 4 + r] = __builtin_amdgcn_exp2f(v);
            }
          l_i[nt] += ((pe[0] + pe[1]) + (pe[2] + pe[3])) +
                     ((pe[4] + pe[5]) + (pe[6] + pe[7]));
#pragma unroll
          for (int mt = 0; mt < 2; mt++) {
            union { h16x2 h[2]; uint2 u; } w;
            w.h[0] = __builtin_amdgcn_cvt_pkrtz(pe[mt * 4 + 0], pe[mt * 4 + 1]);
            w.h[1] = __builtin_amdgcn_cvt_pkrtz(pe[mt * 4 + 2], pe[mt * 4 + 3]);
            *(uint2*)&PsW[(nt * 16 + l16) * 40 + mt * 16 + quad * 4] = w.u;
          }
        }

        const _Float16* Vc = VTsB + cur * 4096;
        f16x8 bp0 = *(const f16x8*)&PsW[l16 * 40 + quad * 8];
        f16x8 bp1 = *(const f16x8*)&PsW[(16 + l16) * 40 + quad * 8];
#pragma unroll
        for (int md = 0; md < 4; md++) {
          f16x8 av = *(const f16x8*)&Vc[(md * 16 + l16) * 64 +
                                        (((kg * 4 + quad) ^ (l16 & 7)) << 3)];
          o[md][0] = MFMA16(av, bp0, o[md][0]);
          o[md][1] = MFMA16(av, bp1, o[md][1]);
        }
      }

      if (pf && vstager) stage_V(nxt, pv0, pv1);
      __syncthreads();
    }

#pragma unroll
    for (int nt = 0; nt < 2; nt++) {
      float r = l_i[nt];
      r += __shfl_xor(r, 16, 64);
      r += __shfl_xor(r, 32, 64);
      l_i[nt] = r;
    }
    float* X = (float*)pool;
    float* ML = (float*)(pool + 53248);
    if (kg == 1) {
#pragma unroll
      for (int md = 0; md < 4; md++)
#pragma unroll
        for (int nt = 0; nt < 2; nt++)
          *(f32x4*)&X[qg * 2048 + (md * 2 + nt) * 256 + lane * 4] = o[md][nt];
      if (quad == 0) {
#pragma unroll
        for (int nt = 0; nt < 2; nt++)
          ML[(qg * 2 + nt) * 16 + l16] = l_i[nt];
      }
    }
    __syncthreads();
    if (kg == 0) {
      _Float16* PsE = (_Float16*)(pool + 32768) + qg * 2304;
      float inv[2];
#pragma unroll
      for (int nt = 0; nt < 2; nt++)
        inv[nt] = 1.0f / (l_i[nt] + ML[(qg * 2 + nt) * 16 + l16]);
#pragma unroll
      for (int md = 0; md < 4; md++)
#pragma unroll
        for (int nt = 0; nt < 2; nt++) {
          f32x4 o1 = *(const f32x4*)&X[qg * 2048 + (md * 2 + nt) * 256 + lane * 4];
          f32x4 ot = o[md][nt] + o1;
          union { h16x2 h[2]; uint2 u; } w;
          w.h[0] = __builtin_amdgcn_cvt_pkrtz(ot[0] * inv[nt], ot[1] * inv[nt]);
          w.h[1] = __builtin_amdgcn_cvt_pkrtz(ot[2] * inv[nt], ot[3] * inv[nt]);
          *(uint2*)&PsE[(nt * 16 + l16) * 72 + md * 16 + quad * 4] = w.u;
        }
      {
        int r = lane >> 1, ch = (lane & 1) * 32;
        const int qgl = qt + qg * 32 + r;
        _Float16* orow = out + (size_t)(b * S_LEN + qgl) * DMODEL + h * HD + ch;
#pragma unroll
        for (int i = 0; i < 4; i++)
          *(uint4*)(orow + i * 8) = *(const uint4*)&PsE[r * 72 + ch + i * 8];
      }
    }
  };

  run_pass(p * 128);
  run_pass((15 - p) * 128);
}

// ---------------- launcher ----------------
extern "C" void kernel_launch(void* const* d_in, const int* in_sizes, int n_in,
                              void* d_out, int out_size, void* d_ws, size_t ws_size,
                              hipStream_t stream) {
  const float* x = (const float*)d_in[0];
  const float* w_attn = (const float*)d_in[1];
  const float* b_attn = (const float*)d_in[2];
  const float* w_proj = (const float*)d_in[3];
  const float* b_proj = (const float*)d_in[4];
  float* outp = (float*)d_out;

  char* ws = (char*)d_ws;
  _Float16* x16 = (_Float16*)ws;                         // 16,777,216 B
  _Float16* wTa = (_Float16*)(ws + 16777216);            //  6,291,456 B
  _Float16* wTp = (_Float16*)(ws + 16777216 + 6291456);  //  2,097,152 B
  _Float16* qkv = (_Float16*)(ws + 25165824);            // 50,331,648 B
  _Float16* abuf = (_Float16*)(ws + 75497472);           // 16,777,216 B

  const int nx = BTOT * S_LEN * DMODEL;

  cvt_f32_f16_k<<<8192, 256, 0, stream>>>(x, x16, nx);
  transpose_cvt_k<<<dim3(QKV_LD / 32, DMODEL / 32), dim3(32, 8), 0, stream>>>(
      w_attn, wTa, DMODEL, QKV_LD);
  transpose_cvt_k<<<dim3(DMODEL / 32, DMODEL / 32), dim3(32, 8), 0, stream>>>(
      w_proj, wTp, DMODEL, DMODEL);

  gemm256_k<<<dim3(QKV_LD / 256, BTOT * S_LEN / 256), 512, 0, stream>>>(
      x16, wTa, b_attn, qkv, BTOT * S_LEN, QKV_LD, DMODEL);

  attn_k<<<dim3(BTOT * NHEAD, 8), 512, 0, stream>>>(qkv, abuf);

  gemm_bt_k<1><<<dim3(DMODEL / 128, BTOT * S_LEN / 128), 256, 0, stream>>>(
      abuf, wTp, b_proj, outp, BTOT * S_LEN, DMODEL, DMODEL);
}